// Round 4
// baseline (425.414 us; speedup 1.0000x reference)
//
#include <hip/hip_runtime.h>

#define H_ 1024
#define W_ 1024
#define RAD 30
#define EPSF 1.3f
#define SH 16            // output rows per block
#define NSEG (H_ / SH)   // 64 y-segments
#define NXCD 8

// padded LDS index: breaks stride-4-float bank pattern on prefix reads
__device__ __forceinline__ int padidx(int i) { return i + (i >> 3); }
#define PSZ (W_ + (W_ >> 3) + 1)   // padidx(1024)=1152 -> 1153 entries

__device__ __forceinline__ float wscan(float v, int lane) {
#pragma unroll
    for (int d = 1; d < 64; d <<= 1) {
        const float t = __shfl_up(v, d, 64);
        if (lane >= d) v += t;
    }
    return v;
}

// ---------------------------------------------------------------------------
// fused_ab: per (plane, 16-row segment) block (XCD-swizzled 1D grid).
// Vertical sliding sums of {R, I, R*I, R*R} in registers (4 cols/thread,
// full row => no x-halo); per row an in-LDS horizontal prefix scan gives the
// 2D box sums; solve a, b; write a, b only.
// ---------------------------------------------------------------------------
__global__ __launch_bounds__(256, 4)
void fused_ab(const float* __restrict__ I, const float* __restrict__ R,
              long long in_off, int nb,
              float* __restrict__ A, float* __restrict__ Bv)
{
    __shared__ float P[4][PSZ];   // single-buffered prefix arrays
    __shared__ float wt[4][4];    // per-wave scan totals

    // bijective XCD swizzle: each XCD gets a contiguous run of blocks
    // (nb = NSEG*pc, NSEG=64 => nb % 8 == 0 always)
    const int q = nb / NXCD;
    const int bid = (int)blockIdx.x;
    const int sbid = (bid % NXCD) * q + bid / NXCD;
    const int seg = sbid % NSEG;
    const int pl  = sbid / NSEG;

    const int tid = threadIdx.x;
    const int lane = tid & 63, wid = tid >> 6;
    const int x0 = tid * 4;
    const int y0 = seg * SH;
    const long long pb = (long long)pl * (long long)(H_ * W_);
    const long long ib = in_off + pb;

    float icx[4];
#pragma unroll
    for (int j = 0; j < 4; ++j) {
        const int x = x0 + j;
        icx[j] = 1.0f / (float)(min(x + RAD, W_ - 1) - max(x - RAD, 0) + 1);
    }

    float s[4][4];   // running vertical sums [field][col]
#pragma unroll
    for (int f = 0; f < 4; ++f)
#pragma unroll
        for (int j = 0; j < 4; ++j) s[f][j] = 0.0f;

    // warm-up rows [y0-RAD, y0+RAD] clipped
    {
        const int ylo = max(0, y0 - RAD), yhi = min(H_ - 1, y0 + RAD);
#pragma unroll 4
        for (int yy = ylo; yy <= yhi; ++yy) {
            const float4 r4 = *(const float4*)(R + ib + (long long)yy * W_ + x0);
            const float4 i4 = *(const float4*)(I + ib + (long long)yy * W_ + x0);
            const float rv[4] = {r4.x, r4.y, r4.z, r4.w};
            const float iv[4] = {i4.x, i4.y, i4.z, i4.w};
#pragma unroll
            for (int j = 0; j < 4; ++j) {
                s[0][j] += rv[j];
                s[1][j] += iv[j];
                s[2][j] += rv[j] * iv[j];
                s[3][j] += rv[j] * rv[j];
            }
        }
    }

    for (int y = y0; y < y0 + SH; ++y) {
        // local + wave scan per field
        float ps[4][4], tot[4], wsc[4];
#pragma unroll
        for (int f = 0; f < 4; ++f) {
            ps[f][0] = s[f][0];
            ps[f][1] = ps[f][0] + s[f][1];
            ps[f][2] = ps[f][1] + s[f][2];
            ps[f][3] = ps[f][2] + s[f][3];
            tot[f] = ps[f][3];
            wsc[f] = wscan(tot[f], lane);
            if (lane == 63) wt[f][wid] = wsc[f];
        }
        __syncthreads();   // b1: wt visible

#pragma unroll
        for (int f = 0; f < 4; ++f) {
            float woff = 0.0f;
#pragma unroll
            for (int w = 0; w < 4; ++w)
                if (w < wid) woff += wt[f][w];
            const float ex = woff + wsc[f] - tot[f];  // exclusive prefix at x0
#pragma unroll
            for (int j = 0; j < 4; ++j)
                P[f][padidx(x0 + 1 + j)] = ex + ps[f][j];
        }
        if (tid == 0) {
#pragma unroll
            for (int f = 0; f < 4; ++f) P[f][0] = 0.0f;   // padidx(0)==0
        }
        __syncthreads();   // b2: P visible

        const float icy = 1.0f / (float)(min(y + RAD, H_ - 1) - max(y - RAD, 0) + 1);
        float av[4], bvv[4];
#pragma unroll
        for (int j = 0; j < 4; ++j) {
            const int x = x0 + j;
            const int hi = padidx(min(x + RAD + 1, W_));
            const int lo = padidx(max(x - RAD, 0));
            const float SR = P[0][hi] - P[0][lo];
            const float SI = P[1][hi] - P[1][lo];
            const float SP = P[2][hi] - P[2][lo];
            const float SQ = P[3][hi] - P[3][lo];
            const float invN = icx[j] * icy;
            const float mR = SR * invN, mI = SI * invN;
            const float a = (SP * invN - mR * mI) / (SQ * invN - mR * mR + EPSF);
            av[j] = a;
            bvv[j] = mI - a * mR;
        }
        const long long ob = pb + (long long)y * W_ + x0;
        *(float4*)(A + ob)  = make_float4(av[0], av[1], av[2], av[3]);
        *(float4*)(Bv + ob) = make_float4(bvv[0], bvv[1], bvv[2], bvv[3]);

        // slide vertical window (loads overlap next round's b1 wait)
        const int ya = y + RAD + 1, ys = y - RAD;
        if (ya < H_) {
            const float4 r4 = *(const float4*)(R + ib + (long long)ya * W_ + x0);
            const float4 i4 = *(const float4*)(I + ib + (long long)ya * W_ + x0);
            const float rv[4] = {r4.x, r4.y, r4.z, r4.w};
            const float iv[4] = {i4.x, i4.y, i4.z, i4.w};
#pragma unroll
            for (int j = 0; j < 4; ++j) {
                s[0][j] += rv[j];
                s[1][j] += iv[j];
                s[2][j] += rv[j] * iv[j];
                s[3][j] += rv[j] * rv[j];
            }
        }
        if (ys >= 0) {
            const float4 r4 = *(const float4*)(R + ib + (long long)ys * W_ + x0);
            const float4 i4 = *(const float4*)(I + ib + (long long)ys * W_ + x0);
            const float rv[4] = {r4.x, r4.y, r4.z, r4.w};
            const float iv[4] = {i4.x, i4.y, i4.z, i4.w};
#pragma unroll
            for (int j = 0; j < 4; ++j) {
                s[0][j] -= rv[j];
                s[1][j] -= iv[j];
                s[2][j] -= rv[j] * iv[j];
                s[3][j] -= rv[j] * rv[j];
            }
        }
    }
}

// ---------------------------------------------------------------------------
// fused_cd: same walking structure over {a, b}; out = mean_a * R + mean_b.
// ---------------------------------------------------------------------------
__global__ __launch_bounds__(256, 4)
void fused_cd(const float* __restrict__ A, const float* __restrict__ Bv,
              const float* __restrict__ Rimg, long long in_off, int nb,
              float* __restrict__ out)
{
    __shared__ float P[2][PSZ];
    __shared__ float wt[2][4];

    const int q = nb / NXCD;
    const int bid = (int)blockIdx.x;
    const int sbid = (bid % NXCD) * q + bid / NXCD;
    const int seg = sbid % NSEG;
    const int pl  = sbid / NSEG;

    const int tid = threadIdx.x;
    const int lane = tid & 63, wid = tid >> 6;
    const int x0 = tid * 4;
    const int y0 = seg * SH;
    const long long pb = (long long)pl * (long long)(H_ * W_);
    const long long ib = in_off + pb;

    float icx[4];
#pragma unroll
    for (int j = 0; j < 4; ++j) {
        const int x = x0 + j;
        icx[j] = 1.0f / (float)(min(x + RAD, W_ - 1) - max(x - RAD, 0) + 1);
    }

    float s[2][4];
#pragma unroll
    for (int f = 0; f < 2; ++f)
#pragma unroll
        for (int j = 0; j < 4; ++j) s[f][j] = 0.0f;

    {
        const int ylo = max(0, y0 - RAD), yhi = min(H_ - 1, y0 + RAD);
#pragma unroll 4
        for (int yy = ylo; yy <= yhi; ++yy) {
            const float4 a4 = *(const float4*)(A + pb + (long long)yy * W_ + x0);
            const float4 b4 = *(const float4*)(Bv + pb + (long long)yy * W_ + x0);
            const float av[4] = {a4.x, a4.y, a4.z, a4.w};
            const float bv[4] = {b4.x, b4.y, b4.z, b4.w};
#pragma unroll
            for (int j = 0; j < 4; ++j) { s[0][j] += av[j]; s[1][j] += bv[j]; }
        }
    }

    for (int y = y0; y < y0 + SH; ++y) {
        float ps[2][4], tot[2], wsc[2];
#pragma unroll
        for (int f = 0; f < 2; ++f) {
            ps[f][0] = s[f][0];
            ps[f][1] = ps[f][0] + s[f][1];
            ps[f][2] = ps[f][1] + s[f][2];
            ps[f][3] = ps[f][2] + s[f][3];
            tot[f] = ps[f][3];
            wsc[f] = wscan(tot[f], lane);
            if (lane == 63) wt[f][wid] = wsc[f];
        }
        __syncthreads();   // b1

#pragma unroll
        for (int f = 0; f < 2; ++f) {
            float woff = 0.0f;
#pragma unroll
            for (int w = 0; w < 4; ++w)
                if (w < wid) woff += wt[f][w];
            const float ex = woff + wsc[f] - tot[f];
#pragma unroll
            for (int j = 0; j < 4; ++j)
                P[f][padidx(x0 + 1 + j)] = ex + ps[f][j];
        }
        if (tid == 0) { P[0][0] = 0.0f; P[1][0] = 0.0f; }
        __syncthreads();   // b2

        const float icy = 1.0f / (float)(min(y + RAD, H_ - 1) - max(y - RAD, 0) + 1);
        const long long og = ib + (long long)y * W_ + x0;
        const float4 r4 = *(const float4*)(Rimg + og);
        const float rv[4] = {r4.x, r4.y, r4.z, r4.w};
        float ov[4];
#pragma unroll
        for (int j = 0; j < 4; ++j) {
            const int x = x0 + j;
            const int hi = padidx(min(x + RAD + 1, W_));
            const int lo = padidx(max(x - RAD, 0));
            const float SA = P[0][hi] - P[0][lo];
            const float SB = P[1][hi] - P[1][lo];
            const float invN = icx[j] * icy;
            ov[j] = (SA * invN) * rv[j] + SB * invN;
        }
        *(float4*)(out + og) = make_float4(ov[0], ov[1], ov[2], ov[3]);

        const int ya = y + RAD + 1, ys = y - RAD;
        if (ya < H_) {
            const float4 a4 = *(const float4*)(A + pb + (long long)ya * W_ + x0);
            const float4 b4 = *(const float4*)(Bv + pb + (long long)ya * W_ + x0);
            const float av[4] = {a4.x, a4.y, a4.z, a4.w};
            const float bv[4] = {b4.x, b4.y, b4.z, b4.w};
#pragma unroll
            for (int j = 0; j < 4; ++j) { s[0][j] += av[j]; s[1][j] += bv[j]; }
        }
        if (ys >= 0) {
            const float4 a4 = *(const float4*)(A + pb + (long long)ys * W_ + x0);
            const float4 b4 = *(const float4*)(Bv + pb + (long long)ys * W_ + x0);
            const float av[4] = {a4.x, a4.y, a4.z, a4.w};
            const float bv[4] = {b4.x, b4.y, b4.z, b4.w};
#pragma unroll
            for (int j = 0; j < 4; ++j) { s[0][j] -= av[j]; s[1][j] -= bv[j]; }
        }
    }
}

// ---------------------------------------------------------------------------
extern "C" void kernel_launch(void* const* d_in, const int* in_sizes, int n_in,
                              void* d_out, int out_size, void* d_ws, size_t ws_size,
                              hipStream_t stream)
{
    const float* I = (const float*)d_in[0];   // image to filter
    const float* R = (const float*)d_in[1];   // guidance image
    float* out = (float*)d_out;

    const long long plane = (long long)H_ * W_;
    const int P_ = (int)(in_sizes[0] / plane);            // 24 planes
    const size_t arr_pb = (size_t)plane * sizeof(float);  // 4 MB/plane/array

    int CH = (int)(ws_size / (2 * arr_pb));   // only a, b live in scratch
    if (CH > P_) CH = P_;
    if (CH < 1) CH = 1;

    float* A  = (float*)d_ws;
    float* Bv = A + (size_t)CH * plane;

    for (int p0 = 0; p0 < P_; p0 += CH) {
        const int pc = (P_ - p0 < CH) ? (P_ - p0) : CH;
        const long long in_off = (long long)p0 * plane;
        const int nb = NSEG * pc;   // NSEG=64 => nb % 8 == 0

        hipLaunchKernelGGL(fused_ab, dim3(nb), dim3(256), 0, stream,
                           I, R, in_off, nb, A, Bv);
        hipLaunchKernelGGL(fused_cd, dim3(nb), dim3(256), 0, stream,
                           A, Bv, R, in_off, nb, out);
    }
}